// Round 7
// baseline (994.924 us; speedup 1.0000x reference)
//
#include <hip/hip_runtime.h>
#include <hip/hip_bf16.h>

// Few-shot matching-network head + Conv4 backbone (MI355X, gfx950). Round 7.
//
// R6: 764 us, ~720 of it conv1 (direct VALU form stuck at 6.8 TF: per-tap
// weight refetch + pressure; VALUBusy 45% but ~90% non-FMA ops). This round
// conv1 joins the MFMA path:
//  - fsc_im2col1_k: builds conv1's B-operand in EXACT MFMA fragment layout
//    [img][ctile=112][lane=64][j=8] bf16, k = ci*9 + (kh*3+kw), k>=27 -> 0.
//  - fsc_gemm1_k: K=32 single-step GEMM, 2 B-frags + 4 A-frags + 8 MFMA per
//    32-col wave-tile; epilogue identical to convm (NHWC 44-pad, bias, ReLU).
//  - conv4 now per-chunk (c3full dropped); emb is a fixed ws region.
// conv2/3/4 MFMA kernels + head proven r5/r6 (absmax 0.0039).

#define BB 8
#define SS 25
#define TT 75
#define CC 5
#define DD 2304
#define NSUP 200
#define NTGT 600
#define NTOT 800
#define EPSF 1e-8f

typedef __attribute__((ext_vector_type(8))) short bf16x8;
typedef __attribute__((ext_vector_type(4))) float f32x4;

__device__ __forceinline__ float load_ext(const void* p, size_t idx, int isf32) {
  if (isf32) return ((const float*)p)[idx];
  unsigned short u = ((const unsigned short*)p)[idx];
  union { unsigned int i; float f; } v;
  v.i = ((unsigned int)u) << 16;
  return v.f;
}

// ---- dtype probe (proven r3-r6): flag=1 => external data is fp32 ----
__global__ void fsc_probe_dtype_k(const unsigned short* __restrict__ w2raw,
                                  int nelems, int* __restrict__ flag) {
  __shared__ int cnt;
  if (threadIdx.x == 0) cnt = 0;
  __syncthreads();
  int local = 0;
  for (int i = threadIdx.x; i < nelems; i += 256) {
    unsigned short u = w2raw[i];
    int ex = (u >> 7) & 0xFF;
    if (ex != 0 && (ex < 0x69 || ex > 0x84)) local++;
  }
  atomicAdd(&cnt, local);
  __syncthreads();
  if (threadIdx.x == 0) *flag = (cnt > nelems / 8) ? 1 : 0;
}

// ---- conv1 weight repack -> A-frag layout [t=4][lane=64][j=8] bf16.
//      co = t*16 + (lane&15), k = (lane>>4)*8 + j; W1 idx = co*27 + k; k>=27 -> 0.
__global__ void fsc_repack_w1f_k(const void* __restrict__ W,
                                 __hip_bfloat16* __restrict__ Wf,
                                 const int* __restrict__ flag) {
  const int isf32 = *flag;
  int i = blockIdx.x * blockDim.x + threadIdx.x;
  if (i >= 2048) return;
  int j = i & 7;
  int lane = (i >> 3) & 63;
  int t = i >> 9;
  int k = (lane >> 4) * 8 + j;
  int co = t * 16 + (lane & 15);
  float v = (k < 27) ? load_ext(W, (size_t)co * 27 + k, isf32) : 0.f;
  Wf[i] = __float2bfloat16(v);
}

// ---- conv2/3/4 weight repack: OIHW [64][64][3][3] -> bf16 A-frag order ----
__global__ void fsc_repack_wm_k(const void* __restrict__ W,
                                __hip_bfloat16* __restrict__ Wf,
                                const int* __restrict__ flag) {
  const int isf32 = *flag;
  int o = blockIdx.x * blockDim.x + threadIdx.x;
  if (o >= 36864) return;
  int j = o & 7;
  int lane = (o >> 3) & 63;
  int t = (o >> 9) & 3;
  int kk = o >> 11;       // 0..17
  int s = kk & 1;
  int khw = kk >> 1;      // kh*3+kw
  int kh = khw / 3, kw = khw - kh * 3;
  int co = t * 16 + (lane & 15);
  int ci = s * 32 + (lane >> 4) * 8 + j;
  float v = load_ext(W, (size_t)((co * 64 + ci) * 3 + kh) * 3 + kw, isf32);
  Wf[o] = __float2bfloat16(v);
}

// ---- zero the 1-px border of an NHWC-padded [N][P][P][64] bf16 buffer ----
template <int P>
__global__ void fsc_zero_border_k(__hip_bfloat16* __restrict__ buf, int N) {
  int i = blockIdx.x * blockDim.x + threadIdx.x;
  const int RP = 4 * P - 4;
  if (i >= N * RP * 64) return;
  int c = i & 63;
  int r = (i >> 6) % RP;
  int n = (i >> 6) / RP;
  int row, colp;
  if (r < P) { row = 0; colp = r; }
  else if (r < 2 * P) { row = P - 1; colp = r - P; }
  else if (r < 3 * P - 2) { row = r - 2 * P + 1; colp = 0; }
  else { row = r - (3 * P - 2) + 1; colp = P - 1; }
  buf[(((size_t)n * P + row) * P + colp) * 64 + c] = __float2bfloat16(0.f);
}

// ---- conv1 im2col: ext [img][3][84][84] -> B-frag buf [img][112][64][8] bf16.
//      col = ct*16 + (lane&15), k = (lane>>4)*8 + j -> (ci=k/9, kh, kw);
//      hi = 2ho+kh, wi = 2wo+kw (pad top/left 0); OOB or k>=27 -> 0. ----
__global__ void fsc_im2col1_k(const void* __restrict__ x, size_t xoff,
                              __hip_bfloat16* __restrict__ buf, int N,
                              const int* __restrict__ flag) {
  const int isf32 = *flag;
  int i = blockIdx.x * blockDim.x + threadIdx.x;
  const int lane = i & 63;
  const int wid = i >> 6;
  const int img = wid / 112;
  const int ct = wid - img * 112;
  if (img >= N) return;
  const int nidx = lane & 15, quad = lane >> 4;
  const int col = ct * 16 + nidx;
  const bool cv = col < 1764;
  const int ho = cv ? col / 42 : 0;
  const int wo = cv ? col - ho * 42 : 0;
  const size_t base = xoff + (size_t)img * 21168;
  union { unsigned short u[8]; uint4 q; } pk;
#pragma unroll
  for (int j = 0; j < 8; ++j) {
    const int k = quad * 8 + j;
    float v = 0.f;
    if (k < 27 && cv) {
      const int ci = k / 9;
      const int r = k - ci * 9;
      const int kh = r / 3, kw = r - kh * 3;
      const int hi = 2 * ho + kh, wi = 2 * wo + kw;
      if (hi < 84 && wi < 84) v = load_ext(x, base + (ci * 84 + hi) * 84 + wi, isf32);
    }
    pk.u[j] = __bfloat16_as_ushort(__float2bfloat16(v));
  }
  *(uint4*)(void*)(buf + ((size_t)(img * 112 + ct) * 64 + lane) * 8) = pk.q;
}

// ---- conv1 GEMM: M=64 co, K=32, N=1764 cols. Wave = 32 cols x 64 co,
//      single k-step: 2 B-frags + 4 A-frags + 8 MFMA. Out: NHWC 44-pad. ----
__global__ void fsc_gemm1_k(const __hip_bfloat16* __restrict__ buf,
                            const __hip_bfloat16* __restrict__ Wf,
                            const void* __restrict__ bias,
                            __hip_bfloat16* __restrict__ out, int N,
                            const int* __restrict__ flag) {
  const int wid = blockIdx.x * 4 + (threadIdx.x >> 6);
  const int img = wid / 56;
  if (img >= N) return;
  const int tl = wid - img * 56;
  const int lane = threadIdx.x & 63;
  const int nidx = lane & 15, quad = lane >> 4;

  const int col0 = tl * 32 + nidx;
  const int col1 = col0 + 16;
  const bool val0 = col0 < 1764;
  const bool val1 = col1 < 1764;

  const __hip_bfloat16* bp = buf + ((size_t)(img * 112 + tl * 2) * 64 + lane) * 8;
  bf16x8 b0 = *(const bf16x8*)(const void*)bp;
  bf16x8 b1 = *(const bf16x8*)(const void*)(bp + 512);

  f32x4 acc[2][4];
#pragma unroll
  for (int p = 0; p < 2; ++p)
#pragma unroll
    for (int t = 0; t < 4; ++t) acc[p][t] = (f32x4){0.f, 0.f, 0.f, 0.f};

#pragma unroll
  for (int t = 0; t < 4; ++t) {
    bf16x8 a = *(const bf16x8*)(const void*)(Wf + ((size_t)t * 64 + lane) * 8);
    acc[0][t] = __builtin_amdgcn_mfma_f32_16x16x32_bf16(a, b0, acc[0][t], 0, 0, 0);
    acc[1][t] = __builtin_amdgcn_mfma_f32_16x16x32_bf16(a, b1, acc[1][t], 0, 0, 0);
  }

  const int isf32 = *flag;
#pragma unroll
  for (int p = 0; p < 2; ++p) {
    const bool valid = p == 0 ? val0 : val1;
    const int col = p == 0 ? col0 : col1;
    const int ho = valid ? col / 42 : 0;
    const int wo = valid ? col - ho * 42 : 0;
#pragma unroll
    for (int t = 0; t < 4; ++t) {
      float v[4];
#pragma unroll
      for (int r = 0; r < 4; ++r) {
        const int cout = t * 16 + quad * 4 + r;
        float xv = acc[p][t][r] + load_ext(bias, cout, isf32);
        v[r] = xv > 0.f ? xv : 0.f;
      }
      if (valid) {
        __hip_bfloat16* o = out + (((size_t)img * 44 + (ho + 1)) * 44 + (wo + 1)) * 64 +
                            t * 16 + quad * 4;
        union { unsigned short u[4]; uint2 w; } pk;
#pragma unroll
        for (int r = 0; r < 4; ++r) pk.u[r] = __bfloat16_as_ushort(__float2bfloat16(v[r]));
        *(uint2*)(void*)o = pk.w;
      }
    }
  }
}

// ---- implicit-GEMM MFMA conv (proven r6): 64ci -> 64co, 3x3 stride 2.
template <int HO, int PWI, int PWO, int ROFF, bool EMB_OUT>
__global__ void fsc_convm_k(const __hip_bfloat16* __restrict__ in,
                            const __hip_bfloat16* __restrict__ Wf,
                            const void* __restrict__ bias, void* __restrict__ out,
                            int N, const int* __restrict__ flag) {
  constexpr int TPI = (HO * HO + 31) / 32;
  const int wid = blockIdx.x * 4 + (threadIdx.x >> 6);
  const int img = wid / TPI;
  if (img >= N) return;
  const int tl = wid - img * TPI;
  const int lane = threadIdx.x & 63;
  const int nidx = lane & 15, quad = lane >> 4;

  int col0 = tl * 32 + nidx;
  int col1 = col0 + 16;
  const bool val0 = col0 < HO * HO;
  const bool val1 = col1 < HO * HO;
  if (!val0) col0 = HO * HO - 1;
  if (!val1) col1 = HO * HO - 1;
  const int ho0 = col0 / HO, wo0 = col0 - ho0 * HO;
  const int ho1 = col1 / HO, wo1 = col1 - ho1 * HO;

  const __hip_bfloat16* bsrc0 =
      in + (((size_t)img * PWI + (2 * ho0 + ROFF)) * PWI + (2 * wo0 + ROFF)) * 64 + quad * 8;
  const __hip_bfloat16* bsrc1 =
      in + (((size_t)img * PWI + (2 * ho1 + ROFF)) * PWI + (2 * wo1 + ROFF)) * 64 + quad * 8;
  const __hip_bfloat16* asrc = Wf + lane * 8;

  f32x4 acc[2][4];
#pragma unroll
  for (int p = 0; p < 2; ++p)
#pragma unroll
    for (int t = 0; t < 4; ++t) acc[p][t] = (f32x4){0.f, 0.f, 0.f, 0.f};

#pragma unroll
  for (int kk = 0; kk < 18; ++kk) {
    const int s = kk & 1;
    const int khw = kk >> 1;
    const int kh = khw / 3, kw = khw - kh * 3;
    const int boff = (kh * PWI + kw) * 64 + s * 32;
    bf16x8 b0 = *(const bf16x8*)(const void*)(bsrc0 + boff);
    bf16x8 b1 = *(const bf16x8*)(const void*)(bsrc1 + boff);
#pragma unroll
    for (int t = 0; t < 4; ++t) {
      bf16x8 a = *(const bf16x8*)(const void*)(asrc + (kk * 4 + t) * 512);
      acc[0][t] = __builtin_amdgcn_mfma_f32_16x16x32_bf16(a, b0, acc[0][t], 0, 0, 0);
      acc[1][t] = __builtin_amdgcn_mfma_f32_16x16x32_bf16(a, b1, acc[1][t], 0, 0, 0);
    }
  }

  const int isf32 = *flag;
#pragma unroll
  for (int p = 0; p < 2; ++p) {
    const bool valid = p == 0 ? val0 : val1;
    const int col = p == 0 ? col0 : col1;
    const int ho = p == 0 ? ho0 : ho1;
    const int wo = p == 0 ? wo0 : wo1;
#pragma unroll
    for (int t = 0; t < 4; ++t) {
      float v[4];
#pragma unroll
      for (int r = 0; r < 4; ++r) {
        const int cout = t * 16 + quad * 4 + r;
        float xv = acc[p][t][r] + load_ext(bias, cout, isf32);
        v[r] = xv > 0.f ? xv : 0.f;
      }
      if (valid) {
        if (EMB_OUT) {
          float* o = (float*)out + ((size_t)img * HO * HO + col) * 64 + t * 16 + quad * 4;
          *(f32x4*)(void*)o = (f32x4){v[0], v[1], v[2], v[3]};
        } else {
          __hip_bfloat16* o = (__hip_bfloat16*)out +
                              (((size_t)img * PWO + (ho + 1)) * PWO + (wo + 1)) * 64 +
                              t * 16 + quad * 4;
          union { unsigned short u[4]; uint2 w; } pk;
#pragma unroll
          for (int r = 0; r < 4; ++r) pk.u[r] = __bfloat16_as_ushort(__float2bfloat16(v[r]));
          *(uint2*)(void*)o = pk.w;
        }
      }
    }
  }
}

// ---- head (proven r3-r6; emb rows NHWC-permuted - head is perm-invariant) ----
__global__ void fsc_proto_k(const float* __restrict__ emb_s, const int* __restrict__ y,
                            float* __restrict__ protos) {
  int i = blockIdx.x * blockDim.x + threadIdx.x;
  if (i >= BB * CC * DD) return;
  int d = i % DD;
  int bc = i / DD;
  int c = bc % CC;
  int b = bc / CC;
  float sum = 0.f;
  for (int s = 0; s < SS; ++s) {
    if (y[b * SS + s] % CC == c) sum += emb_s[(size_t)(b * SS + s) * DD + d];
  }
  protos[i] = sum * 0.2f;
}

__global__ void fsc_pnorm_k(const float* __restrict__ protos, float* __restrict__ pn) {
  __shared__ float red[4];
  __shared__ float inv;
  const int bc = blockIdx.x;
  const float* p = protos + (size_t)bc * DD;
  float ss = 0.f;
  for (int d = threadIdx.x; d < DD; d += 256) { float v = p[d]; ss += v * v; }
#pragma unroll
  for (int off = 32; off > 0; off >>= 1) ss += __shfl_down(ss, off);
  if ((threadIdx.x & 63) == 0) red[threadIdx.x >> 6] = ss;
  __syncthreads();
  if (threadIdx.x == 0) {
    float nrm = sqrtf(red[0] + red[1] + red[2] + red[3]);
    nrm = nrm > EPSF ? nrm : EPSF;
    inv = 1.f / nrm;
  }
  __syncthreads();
  float sc = inv;
  for (int d = threadIdx.x; d < DD; d += 256) pn[(size_t)bc * DD + d] = p[d] * sc;
}

__global__ void fsc_preds_k(const float* __restrict__ emb_t, const float* __restrict__ pn,
                            void* __restrict__ out, const int* __restrict__ flag) {
  __shared__ float red[4][6];
  __shared__ float fin[6];
  const int isf32 = *flag;
  const int bt = blockIdx.x;
  const int b = bt / TT;
  const float* et = emb_t + (size_t)bt * DD;
  float e[9];
#pragma unroll
  for (int k = 0; k < 9; ++k) e[k] = et[threadIdx.x + 256 * k];
  float vals[6];
  {
    float ss = 0.f;
#pragma unroll
    for (int k = 0; k < 9; ++k) ss += e[k] * e[k];
    vals[0] = ss;
  }
  const float* pb = pn + (size_t)b * CC * DD;
#pragma unroll
  for (int c = 0; c < CC; ++c) {
    float s = 0.f;
#pragma unroll
    for (int k = 0; k < 9; ++k) s += e[k] * pb[(size_t)c * DD + threadIdx.x + 256 * k];
    vals[1 + c] = s;
  }
#pragma unroll
  for (int v = 0; v < 6; ++v) {
#pragma unroll
    for (int off = 32; off > 0; off >>= 1) vals[v] += __shfl_down(vals[v], off);
  }
  if ((threadIdx.x & 63) == 0) {
#pragma unroll
    for (int v = 0; v < 6; ++v) red[threadIdx.x >> 6][v] = vals[v];
  }
  __syncthreads();
  if (threadIdx.x < 6)
    fin[threadIdx.x] = red[0][threadIdx.x] + red[1][threadIdx.x] +
                       red[2][threadIdx.x] + red[3][threadIdx.x];
  __syncthreads();
  if (threadIdx.x < CC) {
    float nt = sqrtf(fin[0]);
    nt = nt > EPSF ? nt : EPSF;
    float r = fin[1 + threadIdx.x] / nt;
    if (isf32) ((float*)out)[(size_t)bt * CC + threadIdx.x] = r;
    else ((__hip_bfloat16*)out)[(size_t)bt * CC + threadIdx.x] = __float2bfloat16(r);
  }
}

static inline int fsc_cdiv(int a, int b) { return (a + b - 1) / b; }

extern "C" void kernel_launch(void* const* d_in, const int* in_sizes, int n_in,
                              void* d_out, int out_size, void* d_ws, size_t ws_size,
                              hipStream_t stream) {
  const void* xs = d_in[0];
  const void* xt = d_in[1];
  const int* y = (const int*)d_in[2];
  const void* W1 = d_in[3];
  const void* b1 = d_in[4];
  const void* W2 = d_in[5];
  const void* b2 = d_in[6];
  const void* W3 = d_in[7];
  const void* b3 = d_in[8];
  const void* W4 = d_in[9];
  const void* b4 = d_in[10];

  // ---- workspace layout (fixed ~8.3 MB + per-chunk buffers) ----
  char* w = (char*)d_ws;
  int* flag = (int*)w;                      w += 256;
  __hip_bfloat16* Wf1 = (__hip_bfloat16*)w; w += 2048 * 2;
  __hip_bfloat16* Wf2 = (__hip_bfloat16*)w; w += 36864 * 2;
  __hip_bfloat16* Wf3 = (__hip_bfloat16*)w; w += 36864 * 2;
  __hip_bfloat16* Wf4 = (__hip_bfloat16*)w; w += 36864 * 2;
  float* protos = (float*)w;                w += (size_t)BB * CC * DD * 4;
  float* pn = (float*)w;                    w += (size_t)BB * CC * DD * 4;
  float* emb = (float*)w;                   w += (size_t)NTOT * DD * 4;  // 7.37 MB
  char* chunk0 = w;
  const size_t fixedB = (size_t)(w - (char*)d_ws);
  // per-image: im2col B1 + A1(44-pad) + A2(23-pad) + C3(13-pad)
  const size_t szB1 = (size_t)112 * 64 * 8 * 2;   // 114,688
  const size_t szA1 = (size_t)44 * 44 * 64 * 2;   // 247,808
  const size_t szA2 = (size_t)23 * 23 * 64 * 2;   // 67,712
  const size_t szC3 = (size_t)13 * 13 * 64 * 2;   // 21,632
  const size_t perImgB = szB1 + szA1 + szA2 + szC3;  // 451,840

  int CH = 12;
  const int cands[9] = {64, 56, 48, 40, 32, 24, 20, 16, 12};
  for (int k = 0; k < 9; ++k) {
    if (fixedB + (size_t)cands[k] * perImgB <= ws_size) { CH = cands[k]; break; }
  }
  __hip_bfloat16* B1 = (__hip_bfloat16*)chunk0;
  __hip_bfloat16* A1 = (__hip_bfloat16*)(chunk0 + (size_t)CH * szB1);
  __hip_bfloat16* A2 = (__hip_bfloat16*)(chunk0 + (size_t)CH * (szB1 + szA1));
  __hip_bfloat16* C3 = (__hip_bfloat16*)(chunk0 + (size_t)CH * (szB1 + szA1 + szA2));

  // 1. dtype probe + weight repacks
  fsc_probe_dtype_k<<<1, 256, 0, stream>>>((const unsigned short*)W2, 64 * 64 * 9, flag);
  fsc_repack_w1f_k<<<fsc_cdiv(2048, 256), 256, 0, stream>>>(W1, Wf1, flag);
  fsc_repack_wm_k<<<fsc_cdiv(36864, 256), 256, 0, stream>>>(W2, Wf2, flag);
  fsc_repack_wm_k<<<fsc_cdiv(36864, 256), 256, 0, stream>>>(W3, Wf3, flag);
  fsc_repack_wm_k<<<fsc_cdiv(36864, 256), 256, 0, stream>>>(W4, Wf4, flag);

  // 2. zero NHWC borders of chunk buffers (interiors overwritten every chunk)
  fsc_zero_border_k<44><<<fsc_cdiv(CH * (4 * 44 - 4) * 64, 256), 256, 0, stream>>>(A1, CH);
  fsc_zero_border_k<23><<<fsc_cdiv(CH * (4 * 23 - 4) * 64, 256), 256, 0, stream>>>(A2, CH);
  fsc_zero_border_k<13><<<fsc_cdiv(CH * (4 * 13 - 4) * 64, 256), 256, 0, stream>>>(C3, CH);

  // 3. full pipeline per chunk: im2col -> gemm1 -> conv2 -> conv3 -> conv4(emb)
  auto run_set = [&](const void* x, int count, int gbase) {
    for (int off = 0; off < count; off += CH) {
      const int n = (count - off) < CH ? (count - off) : CH;
      fsc_im2col1_k<<<fsc_cdiv(n * 112 * 64, 256), 256, 0, stream>>>(
          x, (size_t)off * 21168, B1, n, flag);
      fsc_gemm1_k<<<fsc_cdiv(n * 56, 4), 256, 0, stream>>>(B1, Wf1, b1, A1, n, flag);
      // conv2: 44-pad -> 21x21 into 23-pad; ROFF=1; TPI=14
      fsc_convm_k<21, 44, 23, 1, false><<<fsc_cdiv(n * 14, 4), 256, 0, stream>>>(
          A1, Wf2, b2, A2, n, flag);
      // conv3: 23-pad -> 11x11 into 13-pad; ROFF=0; TPI=4
      fsc_convm_k<11, 23, 13, 0, false><<<fsc_cdiv(n * 4, 4), 256, 0, stream>>>(
          A2, Wf3, b3, C3, n, flag);
      // conv4: 13-pad -> fp32 emb rows; ROFF=0; TPI=2
      fsc_convm_k<6, 13, 0, 0, true><<<fsc_cdiv(n * 2, 4), 256, 0, stream>>>(
          C3, Wf4, b4, emb + (size_t)(gbase + off) * DD, n, flag);
    }
  };
  run_set(xs, NSUP, 0);
  run_set(xt, NTGT, NSUP);

  // 4. head
  fsc_proto_k<<<fsc_cdiv(BB * CC * DD, 256), 256, 0, stream>>>(emb, y, protos);
  fsc_pnorm_k<<<BB * CC, 256, 0, stream>>>(protos, pn);
  fsc_preds_k<<<NTGT, 256, 0, stream>>>(emb + (size_t)NSUP * DD, pn, d_out, flag);
}

// Round 8
// 461.429 us; speedup vs baseline: 2.1562x; 2.1562x over previous
//
#include <hip/hip_runtime.h>
#include <hip/hip_bf16.h>

// Few-shot matching-network head + Conv4 backbone (MI355X, gfx950). Round 8.
//
// R7: 995 us REGRESSION. Profile: top-5 all harness 0xAA ws-poison fills
// (268 MB => ws_size = 256 MiB!), every kernel <40 us: 81 serialized
// micro-dispatches = launch/dependency latency. Fix: use the big workspace.
//  - CH=400 images/chunk: 3 chunks total -> ~20 dispatches, 10-100x more
//    parallelism per dispatch (conv2 = 1400 blocks at CH=400).
//  - kernel bodies unchanged from r7 (absmax 0.0039 proven).

#define BB 8
#define SS 25
#define TT 75
#define CC 5
#define DD 2304
#define NSUP 200
#define NTGT 600
#define NTOT 800
#define EPSF 1e-8f

typedef __attribute__((ext_vector_type(8))) short bf16x8;
typedef __attribute__((ext_vector_type(4))) float f32x4;

__device__ __forceinline__ float load_ext(const void* p, size_t idx, int isf32) {
  if (isf32) return ((const float*)p)[idx];
  unsigned short u = ((const unsigned short*)p)[idx];
  union { unsigned int i; float f; } v;
  v.i = ((unsigned int)u) << 16;
  return v.f;
}

// ---- dtype probe (proven r3-r7): flag=1 => external data is fp32 ----
__global__ void fsc_probe_dtype_k(const unsigned short* __restrict__ w2raw,
                                  int nelems, int* __restrict__ flag) {
  __shared__ int cnt;
  if (threadIdx.x == 0) cnt = 0;
  __syncthreads();
  int local = 0;
  for (int i = threadIdx.x; i < nelems; i += 256) {
    unsigned short u = w2raw[i];
    int ex = (u >> 7) & 0xFF;
    if (ex != 0 && (ex < 0x69 || ex > 0x84)) local++;
  }
  atomicAdd(&cnt, local);
  __syncthreads();
  if (threadIdx.x == 0) *flag = (cnt > nelems / 8) ? 1 : 0;
}

// ---- conv1 weight repack -> A-frag layout [t=4][lane=64][j=8] bf16 ----
__global__ void fsc_repack_w1f_k(const void* __restrict__ W,
                                 __hip_bfloat16* __restrict__ Wf,
                                 const int* __restrict__ flag) {
  const int isf32 = *flag;
  int i = blockIdx.x * blockDim.x + threadIdx.x;
  if (i >= 2048) return;
  int j = i & 7;
  int lane = (i >> 3) & 63;
  int t = i >> 9;
  int k = (lane >> 4) * 8 + j;
  int co = t * 16 + (lane & 15);
  float v = (k < 27) ? load_ext(W, (size_t)co * 27 + k, isf32) : 0.f;
  Wf[i] = __float2bfloat16(v);
}

// ---- conv2/3/4 weight repack: OIHW [64][64][3][3] -> bf16 A-frag order ----
__global__ void fsc_repack_wm_k(const void* __restrict__ W,
                                __hip_bfloat16* __restrict__ Wf,
                                const int* __restrict__ flag) {
  const int isf32 = *flag;
  int o = blockIdx.x * blockDim.x + threadIdx.x;
  if (o >= 36864) return;
  int j = o & 7;
  int lane = (o >> 3) & 63;
  int t = (o >> 9) & 3;
  int kk = o >> 11;       // 0..17
  int s = kk & 1;
  int khw = kk >> 1;      // kh*3+kw
  int kh = khw / 3, kw = khw - kh * 3;
  int co = t * 16 + (lane & 15);
  int ci = s * 32 + (lane >> 4) * 8 + j;
  float v = load_ext(W, (size_t)((co * 64 + ci) * 3 + kh) * 3 + kw, isf32);
  Wf[o] = __float2bfloat16(v);
}

// ---- zero the 1-px border of an NHWC-padded [N][P][P][64] bf16 buffer ----
template <int P>
__global__ void fsc_zero_border_k(__hip_bfloat16* __restrict__ buf, int N) {
  int i = blockIdx.x * blockDim.x + threadIdx.x;
  const int RP = 4 * P - 4;
  if (i >= N * RP * 64) return;
  int c = i & 63;
  int r = (i >> 6) % RP;
  int n = (i >> 6) / RP;
  int row, colp;
  if (r < P) { row = 0; colp = r; }
  else if (r < 2 * P) { row = P - 1; colp = r - P; }
  else if (r < 3 * P - 2) { row = r - 2 * P + 1; colp = 0; }
  else { row = r - (3 * P - 2) + 1; colp = P - 1; }
  buf[(((size_t)n * P + row) * P + colp) * 64 + c] = __float2bfloat16(0.f);
}

// ---- conv1 im2col: ext [img][3][84][84] -> B-frag buf [img][112][64][8] bf16 ----
__global__ void fsc_im2col1_k(const void* __restrict__ x, size_t xoff,
                              __hip_bfloat16* __restrict__ buf, int N,
                              const int* __restrict__ flag) {
  const int isf32 = *flag;
  int i = blockIdx.x * blockDim.x + threadIdx.x;
  const int lane = i & 63;
  const int wid = i >> 6;
  const int img = wid / 112;
  const int ct = wid - img * 112;
  if (img >= N) return;
  const int nidx = lane & 15, quad = lane >> 4;
  const int col = ct * 16 + nidx;
  const bool cv = col < 1764;
  const int ho = cv ? col / 42 : 0;
  const int wo = cv ? col - ho * 42 : 0;
  const size_t base = xoff + (size_t)img * 21168;
  union { unsigned short u[8]; uint4 q; } pk;
#pragma unroll
  for (int j = 0; j < 8; ++j) {
    const int k = quad * 8 + j;
    float v = 0.f;
    if (k < 27 && cv) {
      const int ci = k / 9;
      const int r = k - ci * 9;
      const int kh = r / 3, kw = r - kh * 3;
      const int hi = 2 * ho + kh, wi = 2 * wo + kw;
      if (hi < 84 && wi < 84) v = load_ext(x, base + (ci * 84 + hi) * 84 + wi, isf32);
    }
    pk.u[j] = __bfloat16_as_ushort(__float2bfloat16(v));
  }
  *(uint4*)(void*)(buf + ((size_t)(img * 112 + ct) * 64 + lane) * 8) = pk.q;
}

// ---- conv1 GEMM: M=64 co, K=32, N=1764 cols; out NHWC 44-pad ----
__global__ void fsc_gemm1_k(const __hip_bfloat16* __restrict__ buf,
                            const __hip_bfloat16* __restrict__ Wf,
                            const void* __restrict__ bias,
                            __hip_bfloat16* __restrict__ out, int N,
                            const int* __restrict__ flag) {
  const int wid = blockIdx.x * 4 + (threadIdx.x >> 6);
  const int img = wid / 56;
  if (img >= N) return;
  const int tl = wid - img * 56;
  const int lane = threadIdx.x & 63;
  const int nidx = lane & 15, quad = lane >> 4;

  const int col0 = tl * 32 + nidx;
  const int col1 = col0 + 16;
  const bool val0 = col0 < 1764;
  const bool val1 = col1 < 1764;

  const __hip_bfloat16* bp = buf + ((size_t)(img * 112 + tl * 2) * 64 + lane) * 8;
  bf16x8 b0 = *(const bf16x8*)(const void*)bp;
  bf16x8 b1 = *(const bf16x8*)(const void*)(bp + 512);

  f32x4 acc[2][4];
#pragma unroll
  for (int p = 0; p < 2; ++p)
#pragma unroll
    for (int t = 0; t < 4; ++t) acc[p][t] = (f32x4){0.f, 0.f, 0.f, 0.f};

#pragma unroll
  for (int t = 0; t < 4; ++t) {
    bf16x8 a = *(const bf16x8*)(const void*)(Wf + ((size_t)t * 64 + lane) * 8);
    acc[0][t] = __builtin_amdgcn_mfma_f32_16x16x32_bf16(a, b0, acc[0][t], 0, 0, 0);
    acc[1][t] = __builtin_amdgcn_mfma_f32_16x16x32_bf16(a, b1, acc[1][t], 0, 0, 0);
  }

  const int isf32 = *flag;
#pragma unroll
  for (int p = 0; p < 2; ++p) {
    const bool valid = p == 0 ? val0 : val1;
    const int col = p == 0 ? col0 : col1;
    const int ho = valid ? col / 42 : 0;
    const int wo = valid ? col - ho * 42 : 0;
#pragma unroll
    for (int t = 0; t < 4; ++t) {
      float v[4];
#pragma unroll
      for (int r = 0; r < 4; ++r) {
        const int cout = t * 16 + quad * 4 + r;
        float xv = acc[p][t][r] + load_ext(bias, cout, isf32);
        v[r] = xv > 0.f ? xv : 0.f;
      }
      if (valid) {
        __hip_bfloat16* o = out + (((size_t)img * 44 + (ho + 1)) * 44 + (wo + 1)) * 64 +
                            t * 16 + quad * 4;
        union { unsigned short u[4]; uint2 w; } pk;
#pragma unroll
        for (int r = 0; r < 4; ++r) pk.u[r] = __bfloat16_as_ushort(__float2bfloat16(v[r]));
        *(uint2*)(void*)o = pk.w;
      }
    }
  }
}

// ---- implicit-GEMM MFMA conv (proven r6/r7): 64ci -> 64co, 3x3 stride 2 ----
template <int HO, int PWI, int PWO, int ROFF, bool EMB_OUT>
__global__ void fsc_convm_k(const __hip_bfloat16* __restrict__ in,
                            const __hip_bfloat16* __restrict__ Wf,
                            const void* __restrict__ bias, void* __restrict__ out,
                            int N, const int* __restrict__ flag) {
  constexpr int TPI = (HO * HO + 31) / 32;
  const int wid = blockIdx.x * 4 + (threadIdx.x >> 6);
  const int img = wid / TPI;
  if (img >= N) return;
  const int tl = wid - img * TPI;
  const int lane = threadIdx.x & 63;
  const int nidx = lane & 15, quad = lane >> 4;

  int col0 = tl * 32 + nidx;
  int col1 = col0 + 16;
  const bool val0 = col0 < HO * HO;
  const bool val1 = col1 < HO * HO;
  if (!val0) col0 = HO * HO - 1;
  if (!val1) col1 = HO * HO - 1;
  const int ho0 = col0 / HO, wo0 = col0 - ho0 * HO;
  const int ho1 = col1 / HO, wo1 = col1 - ho1 * HO;

  const __hip_bfloat16* bsrc0 =
      in + (((size_t)img * PWI + (2 * ho0 + ROFF)) * PWI + (2 * wo0 + ROFF)) * 64 + quad * 8;
  const __hip_bfloat16* bsrc1 =
      in + (((size_t)img * PWI + (2 * ho1 + ROFF)) * PWI + (2 * wo1 + ROFF)) * 64 + quad * 8;
  const __hip_bfloat16* asrc = Wf + lane * 8;

  f32x4 acc[2][4];
#pragma unroll
  for (int p = 0; p < 2; ++p)
#pragma unroll
    for (int t = 0; t < 4; ++t) acc[p][t] = (f32x4){0.f, 0.f, 0.f, 0.f};

#pragma unroll
  for (int kk = 0; kk < 18; ++kk) {
    const int s = kk & 1;
    const int khw = kk >> 1;
    const int kh = khw / 3, kw = khw - kh * 3;
    const int boff = (kh * PWI + kw) * 64 + s * 32;
    bf16x8 b0 = *(const bf16x8*)(const void*)(bsrc0 + boff);
    bf16x8 b1 = *(const bf16x8*)(const void*)(bsrc1 + boff);
#pragma unroll
    for (int t = 0; t < 4; ++t) {
      bf16x8 a = *(const bf16x8*)(const void*)(asrc + (kk * 4 + t) * 512);
      acc[0][t] = __builtin_amdgcn_mfma_f32_16x16x32_bf16(a, b0, acc[0][t], 0, 0, 0);
      acc[1][t] = __builtin_amdgcn_mfma_f32_16x16x32_bf16(a, b1, acc[1][t], 0, 0, 0);
    }
  }

  const int isf32 = *flag;
#pragma unroll
  for (int p = 0; p < 2; ++p) {
    const bool valid = p == 0 ? val0 : val1;
    const int col = p == 0 ? col0 : col1;
    const int ho = p == 0 ? ho0 : ho1;
    const int wo = p == 0 ? wo0 : wo1;
#pragma unroll
    for (int t = 0; t < 4; ++t) {
      float v[4];
#pragma unroll
      for (int r = 0; r < 4; ++r) {
        const int cout = t * 16 + quad * 4 + r;
        float xv = acc[p][t][r] + load_ext(bias, cout, isf32);
        v[r] = xv > 0.f ? xv : 0.f;
      }
      if (valid) {
        if (EMB_OUT) {
          float* o = (float*)out + ((size_t)img * HO * HO + col) * 64 + t * 16 + quad * 4;
          *(f32x4*)(void*)o = (f32x4){v[0], v[1], v[2], v[3]};
        } else {
          __hip_bfloat16* o = (__hip_bfloat16*)out +
                              (((size_t)img * PWO + (ho + 1)) * PWO + (wo + 1)) * 64 +
                              t * 16 + quad * 4;
          union { unsigned short u[4]; uint2 w; } pk;
#pragma unroll
          for (int r = 0; r < 4; ++r) pk.u[r] = __bfloat16_as_ushort(__float2bfloat16(v[r]));
          *(uint2*)(void*)o = pk.w;
        }
      }
    }
  }
}

// ---- head (proven r3-r7; emb rows NHWC-permuted - head is perm-invariant) ----
__global__ void fsc_proto_k(const float* __restrict__ emb_s, const int* __restrict__ y,
                            float* __restrict__ protos) {
  int i = blockIdx.x * blockDim.x + threadIdx.x;
  if (i >= BB * CC * DD) return;
  int d = i % DD;
  int bc = i / DD;
  int c = bc % CC;
  int b = bc / CC;
  float sum = 0.f;
  for (int s = 0; s < SS; ++s) {
    if (y[b * SS + s] % CC == c) sum += emb_s[(size_t)(b * SS + s) * DD + d];
  }
  protos[i] = sum * 0.2f;
}

__global__ void fsc_pnorm_k(const float* __restrict__ protos, float* __restrict__ pn) {
  __shared__ float red[4];
  __shared__ float inv;
  const int bc = blockIdx.x;
  const float* p = protos + (size_t)bc * DD;
  float ss = 0.f;
  for (int d = threadIdx.x; d < DD; d += 256) { float v = p[d]; ss += v * v; }
#pragma unroll
  for (int off = 32; off > 0; off >>= 1) ss += __shfl_down(ss, off);
  if ((threadIdx.x & 63) == 0) red[threadIdx.x >> 6] = ss;
  __syncthreads();
  if (threadIdx.x == 0) {
    float nrm = sqrtf(red[0] + red[1] + red[2] + red[3]);
    nrm = nrm > EPSF ? nrm : EPSF;
    inv = 1.f / nrm;
  }
  __syncthreads();
  float sc = inv;
  for (int d = threadIdx.x; d < DD; d += 256) pn[(size_t)bc * DD + d] = p[d] * sc;
}

__global__ void fsc_preds_k(const float* __restrict__ emb_t, const float* __restrict__ pn,
                            void* __restrict__ out, const int* __restrict__ flag) {
  __shared__ float red[4][6];
  __shared__ float fin[6];
  const int isf32 = *flag;
  const int bt = blockIdx.x;
  const int b = bt / TT;
  const float* et = emb_t + (size_t)bt * DD;
  float e[9];
#pragma unroll
  for (int k = 0; k < 9; ++k) e[k] = et[threadIdx.x + 256 * k];
  float vals[6];
  {
    float ss = 0.f;
#pragma unroll
    for (int k = 0; k < 9; ++k) ss += e[k] * e[k];
    vals[0] = ss;
  }
  const float* pb = pn + (size_t)b * CC * DD;
#pragma unroll
  for (int c = 0; c < CC; ++c) {
    float s = 0.f;
#pragma unroll
    for (int k = 0; k < 9; ++k) s += e[k] * pb[(size_t)c * DD + threadIdx.x + 256 * k];
    vals[1 + c] = s;
  }
#pragma unroll
  for (int v = 0; v < 6; ++v) {
#pragma unroll
    for (int off = 32; off > 0; off >>= 1) vals[v] += __shfl_down(vals[v], off);
  }
  if ((threadIdx.x & 63) == 0) {
#pragma unroll
    for (int v = 0; v < 6; ++v) red[threadIdx.x >> 6][v] = vals[v];
  }
  __syncthreads();
  if (threadIdx.x < 6)
    fin[threadIdx.x] = red[0][threadIdx.x] + red[1][threadIdx.x] +
                       red[2][threadIdx.x] + red[3][threadIdx.x];
  __syncthreads();
  if (threadIdx.x < CC) {
    float nt = sqrtf(fin[0]);
    nt = nt > EPSF ? nt : EPSF;
    float r = fin[1 + threadIdx.x] / nt;
    if (isf32) ((float*)out)[(size_t)bt * CC + threadIdx.x] = r;
    else ((__hip_bfloat16*)out)[(size_t)bt * CC + threadIdx.x] = __float2bfloat16(r);
  }
}

static inline int fsc_cdiv(int a, int b) { return (a + b - 1) / b; }

extern "C" void kernel_launch(void* const* d_in, const int* in_sizes, int n_in,
                              void* d_out, int out_size, void* d_ws, size_t ws_size,
                              hipStream_t stream) {
  const void* xs = d_in[0];
  const void* xt = d_in[1];
  const int* y = (const int*)d_in[2];
  const void* W1 = d_in[3];
  const void* b1 = d_in[4];
  const void* W2 = d_in[5];
  const void* b2 = d_in[6];
  const void* W3 = d_in[7];
  const void* b3 = d_in[8];
  const void* W4 = d_in[9];
  const void* b4 = d_in[10];

  // ---- workspace layout: fixed ~25.6 MB + 3 big per-chunk buffers ----
  char* w = (char*)d_ws;
  int* flag = (int*)w;                      w += 256;
  __hip_bfloat16* Wf1 = (__hip_bfloat16*)w; w += 2048 * 2;
  __hip_bfloat16* Wf2 = (__hip_bfloat16*)w; w += 36864 * 2;
  __hip_bfloat16* Wf3 = (__hip_bfloat16*)w; w += 36864 * 2;
  __hip_bfloat16* Wf4 = (__hip_bfloat16*)w; w += 36864 * 2;
  float* protos = (float*)w;                w += (size_t)BB * CC * DD * 4;
  float* pn = (float*)w;                    w += (size_t)BB * CC * DD * 4;
  float* emb = (float*)w;                   w += (size_t)NTOT * DD * 4;          // 7.37 MB
  __hip_bfloat16* C3 = (__hip_bfloat16*)w;  w += (size_t)NTOT * 13 * 13 * 64 * 2; // 17.3 MB
  char* chunk0 = w;
  const size_t fixedB = (size_t)(w - (char*)d_ws);
  const size_t szB1 = (size_t)112 * 64 * 8 * 2;   // 114,688 B/img
  const size_t szA1 = (size_t)44 * 44 * 64 * 2;   // 247,808 B/img
  const size_t szA2 = (size_t)23 * 23 * 64 * 2;   //  67,712 B/img
  const size_t perImgB = szB1 + szA1 + szA2;       // 430,208 B/img

  int CH = 50;
  const int cands[5] = {400, 200, 100, 67, 50};
  for (int k = 0; k < 5; ++k) {
    if (fixedB + (size_t)cands[k] * perImgB <= ws_size) { CH = cands[k]; break; }
  }
  __hip_bfloat16* B1 = (__hip_bfloat16*)chunk0;
  __hip_bfloat16* A1 = (__hip_bfloat16*)(chunk0 + (size_t)CH * szB1);
  __hip_bfloat16* A2 = (__hip_bfloat16*)(chunk0 + (size_t)CH * (szB1 + szA1));

  // 1. dtype probe + weight repacks
  fsc_probe_dtype_k<<<1, 256, 0, stream>>>((const unsigned short*)W2, 64 * 64 * 9, flag);
  fsc_repack_w1f_k<<<fsc_cdiv(2048, 256), 256, 0, stream>>>(W1, Wf1, flag);
  fsc_repack_wm_k<<<fsc_cdiv(36864, 256), 256, 0, stream>>>(W2, Wf2, flag);
  fsc_repack_wm_k<<<fsc_cdiv(36864, 256), 256, 0, stream>>>(W3, Wf3, flag);
  fsc_repack_wm_k<<<fsc_cdiv(36864, 256), 256, 0, stream>>>(W4, Wf4, flag);

  // 2. zero NHWC borders (interiors rewritten each chunk; borders stay 0)
  fsc_zero_border_k<44><<<fsc_cdiv(CH * (4 * 44 - 4) * 64, 256), 256, 0, stream>>>(A1, CH);
  fsc_zero_border_k<23><<<fsc_cdiv(CH * (4 * 23 - 4) * 64, 256), 256, 0, stream>>>(A2, CH);
  fsc_zero_border_k<13><<<fsc_cdiv(NTOT * (4 * 13 - 4) * 64, 256), 256, 0, stream>>>(C3, NTOT);

  // 3. big chunks: im2col -> gemm1 -> conv2 -> conv3 (-> C3 full-batch slice)
  auto run_set = [&](const void* x, int count, int gbase) {
    for (int off = 0; off < count; off += CH) {
      const int n = (count - off) < CH ? (count - off) : CH;
      fsc_im2col1_k<<<fsc_cdiv(n * 112 * 64, 256), 256, 0, stream>>>(
          x, (size_t)off * 21168, B1, n, flag);
      fsc_gemm1_k<<<fsc_cdiv(n * 56, 4), 256, 0, stream>>>(B1, Wf1, b1, A1, n, flag);
      fsc_convm_k<21, 44, 23, 1, false><<<fsc_cdiv(n * 14, 4), 256, 0, stream>>>(
          A1, Wf2, b2, A2, n, flag);
      fsc_convm_k<11, 23, 13, 0, false><<<fsc_cdiv(n * 4, 4), 256, 0, stream>>>(
          A2, Wf3, b3, C3 + (size_t)(gbase + off) * 13 * 13 * 64, n, flag);
    }
  };
  run_set(xs, NSUP, 0);
  run_set(xt, NTGT, NSUP);

  // 4. conv4 full batch: 13-pad -> fp32 emb [800][2304]
  fsc_convm_k<6, 13, 0, 0, true><<<fsc_cdiv(NTOT * 2, 4), 256, 0, stream>>>(
      C3, Wf4, b4, emb, NTOT, flag);

  // 5. head
  fsc_proto_k<<<fsc_cdiv(BB * CC * DD, 256), 256, 0, stream>>>(emb, y, protos);
  fsc_pnorm_k<<<BB * CC, 256, 0, stream>>>(protos, pn);
  fsc_preds_k<<<NTGT, 256, 0, stream>>>(emb + (size_t)NSUP * DD, pn, d_out, flag);
}